// Round 2
// baseline (276.493 us; speedup 1.0000x reference)
//
#include <hip/hip_runtime.h>

// Y: 16384 x 2048 fp32 row-major. loss = sum_c |1 - (1/n) * sum_r Y[r][c]^2|
#define NROWS 16384
#define D     2048
#define D4    (D / 4)                      // 512 float4 per row
#define YBLOCKS 256                        // row-stripe blocks
#define ROWS_PER_BLOCK (NROWS / YBLOCKS)   // 64
#define NBLOCKS (2 * YBLOCKS)              // 512 total blocks

// Single fused kernel.
// Phase 1: per-thread sum of squares of 4 consecutive columns over a 64-row
//          stripe (float4 coalesced loads), atomicAdd into colsum[2048].
// Phase 2: last block (fenced counter) reads colsum with agent-scope atomic
//          loads, applies |1 - s/n|, block-reduces, writes out[0].
__global__ void __launch_bounds__(256)
semidef_loss(const float4* __restrict__ Y4, float* __restrict__ colsum,
             unsigned* __restrict__ counter, float* __restrict__ out) {
    const int c4 = blockIdx.x * 256 + threadIdx.x;      // [0, 512)
    const int yb = blockIdx.y;
    const float4* p = Y4 + (size_t)yb * ROWS_PER_BLOCK * D4 + c4;
    float4 acc = make_float4(0.f, 0.f, 0.f, 0.f);
#pragma unroll 16
    for (int r = 0; r < ROWS_PER_BLOCK; ++r) {
        float4 v = p[(size_t)r * D4];
        acc.x += v.x * v.x;
        acc.y += v.y * v.y;
        acc.z += v.z * v.z;
        acc.w += v.w * v.w;
    }
    const int c = c4 * 4;
    atomicAdd(&colsum[c + 0], acc.x);
    atomicAdd(&colsum[c + 1], acc.y);
    atomicAdd(&colsum[c + 2], acc.z);
    atomicAdd(&colsum[c + 3], acc.w);

    // completion counter (release prior atomics, acquire on last)
    __threadfence();
    __shared__ int is_last;
    if (threadIdx.x == 0) {
        unsigned old = __hip_atomic_fetch_add(counter, 1u, __ATOMIC_ACQ_REL,
                                              __HIP_MEMORY_SCOPE_AGENT);
        is_last = (old == NBLOCKS - 1);
    }
    __syncthreads();
    if (!is_last) return;

    // last block: finalize. 256 threads x 8 columns, coalesced.
    float vsum = 0.f;
#pragma unroll
    for (int i = 0; i < 8; ++i) {
        int col = threadIdx.x + 256 * i;
        float s = __hip_atomic_load(&colsum[col], __ATOMIC_RELAXED,
                                    __HIP_MEMORY_SCOPE_AGENT);
        vsum += fabsf(1.0f - s * (1.0f / (float)NROWS));
    }
#pragma unroll
    for (int off = 32; off; off >>= 1)
        vsum += __shfl_down(vsum, off, 64);
    __shared__ float lds[4];
    const int lane = threadIdx.x & 63;
    const int wv   = threadIdx.x >> 6;
    if (lane == 0) lds[wv] = vsum;
    __syncthreads();
    if (threadIdx.x == 0)
        out[0] = lds[0] + lds[1] + lds[2] + lds[3];
}

extern "C" void kernel_launch(void* const* d_in, const int* in_sizes, int n_in,
                              void* d_out, int out_size, void* d_ws, size_t ws_size,
                              hipStream_t stream) {
    const float4* Y4 = (const float4*)d_in[0];
    float* out       = (float*)d_out;
    float* colsum    = (float*)d_ws;                 // 2048 floats
    unsigned* counter = (unsigned*)((char*)d_ws + D * sizeof(float));

    // d_ws is poisoned 0xAA before every launch: zero colsum + counter.
    hipMemsetAsync(d_ws, 0, D * sizeof(float) + sizeof(unsigned), stream);

    semidef_loss<<<dim3(2, YBLOCKS), 256, 0, stream>>>(Y4, colsum, counter, out);
}

// Round 3
// 194.744 us; speedup vs baseline: 1.4198x; 1.4198x over previous
//
#include <hip/hip_runtime.h>

// Y: 16384 x 2048 fp32 row-major. loss = sum_c |1 - (1/n) * sum_r Y[r][c]^2|
#define NROWS 16384
#define D     2048
#define D4    (D / 4)                       // 512 float4 per row
#define YBLOCKS 512                         // row-stripe blocks
#define ROWS_PER_BLOCK (NROWS / YBLOCKS)    // 32 rows per stripe
// P: [YBLOCKS][D] floats = 4 MB of partials in d_ws
// ws2: [32] floats of per-block loss partials, after P

// K1: per-column sum of squares over a 32-row stripe.
// grid (2, 512) x 256 threads. Thread owns 4 consecutive columns (1 float4).
// Fully coalesced 16B/lane; plain stores (no atomics).
__global__ void __launch_bounds__(256)
colsq_partial(const float4* __restrict__ Y4, float4* __restrict__ P4) {
    const int c4 = blockIdx.x * 256 + threadIdx.x;      // [0, 512)
    const int yb = blockIdx.y;
    const float4* p = Y4 + (size_t)yb * ROWS_PER_BLOCK * D4 + c4;
    float4 acc = make_float4(0.f, 0.f, 0.f, 0.f);
#pragma unroll 8
    for (int r = 0; r < ROWS_PER_BLOCK; ++r) {
        float4 v = p[(size_t)r * D4];
        acc.x += v.x * v.x;
        acc.y += v.y * v.y;
        acc.z += v.z * v.z;
        acc.w += v.w * v.w;
    }
    P4[(size_t)yb * D4 + c4] = acc;
}

// K2: reduce P over yb per column, apply |1 - s/n|, reduce 64 columns/block.
// grid 32 x 256. Block b owns cols [b*64, b*64+64); 4 threads per column,
// each sums 128 ybs. Coalesced: lanes read 64 consecutive floats per row.
__global__ void __launch_bounds__(256)
col_finalize(const float* __restrict__ P, float* __restrict__ ws2) {
    const int col  = blockIdx.x * 64 + (threadIdx.x & 63);
    const int part = threadIdx.x >> 6;                  // 0..3
    float s = 0.f;
#pragma unroll 8
    for (int i = 0; i < YBLOCKS / 4; ++i) {
        int yb = part * (YBLOCKS / 4) + i;
        s += P[yb * D + col];
    }
    __shared__ float lds[256];
    lds[threadIdx.x] = s;
    __syncthreads();
    if (threadIdx.x < 64) {
        float tot = lds[threadIdx.x] + lds[threadIdx.x + 64] +
                    lds[threadIdx.x + 128] + lds[threadIdx.x + 192];
        float v = fabsf(1.0f - tot * (1.0f / (float)NROWS));
#pragma unroll
        for (int off = 32; off; off >>= 1)
            v += __shfl_down(v, off, 64);
        if (threadIdx.x == 0) ws2[blockIdx.x] = v;
    }
}

// K3: one wave sums the 32 block partials and writes the scalar.
__global__ void __launch_bounds__(64)
final_sum(const float* __restrict__ ws2, float* __restrict__ out) {
    float v = (threadIdx.x < 32) ? ws2[threadIdx.x] : 0.f;
#pragma unroll
    for (int off = 32; off; off >>= 1)
        v += __shfl_down(v, off, 64);
    if (threadIdx.x == 0) out[0] = v;
}

extern "C" void kernel_launch(void* const* d_in, const int* in_sizes, int n_in,
                              void* d_out, int out_size, void* d_ws, size_t ws_size,
                              hipStream_t stream) {
    const float4* Y4 = (const float4*)d_in[0];
    float* out = (float*)d_out;
    float* P   = (float*)d_ws;                               // 4 MB partials
    float* ws2 = (float*)((char*)d_ws + (size_t)YBLOCKS * D * sizeof(float));

    colsq_partial<<<dim3(2, YBLOCKS), 256, 0, stream>>>(Y4, (float4*)P);
    col_finalize<<<dim3(32), 256, 0, stream>>>(P, ws2);
    final_sum<<<dim3(1), 64, 0, stream>>>(ws2, out);
}